// Round 1
// baseline (139.321 us; speedup 1.0000x reference)
//
#include <hip/hip_runtime.h>

#define BB 32
#define VV 48
#define CC 24
#define AA 6
#define NCODES 10001
#define DD 128
#define HH 128
#define OUTN 167
#define G3 384  // 3*H

__device__ __forceinline__ float fast_tanh(float x) {
    // tanh(x) = 1 - 2/(1+exp(2x)); stable at both extremes in fp32
    return 1.0f - 2.0f / (1.0f + __expf(2.0f * x));
}
__device__ __forceinline__ float fast_sigmoid(float x) {
    return 1.0f / (1.0f + __expf(-x));
}

// K1: P1[c,e] = sum_d emb[c,d]*W[e,d]; P2[c,e] = sum_d emb[c,d]*W[e,128+d]
__global__ __launch_bounds__(256) void k_precompute(
    const float* __restrict__ emb, const float* __restrict__ w_basic,
    float* __restrict__ P1, float* __restrict__ P2, int nrows)
{
    __shared__ float embs[8][128];
    int row0 = blockIdx.x * 8;
    int t = threadIdx.x;
    for (int i = t; i < 8 * 128; i += 256) {
        int r = i >> 7, d = i & 127;
        int row = row0 + r;
        embs[r][d] = (row < nrows) ? emb[row * 128 + d] : 0.0f;
    }
    __syncthreads();
    int e = t & 127, sel = t >> 7;
    const float* wrow = w_basic + e * 256 + sel * 128;
    float acc[8] = {0, 0, 0, 0, 0, 0, 0, 0};
#pragma unroll 8
    for (int d = 0; d < 128; ++d) {
        float w = wrow[d];
#pragma unroll
        for (int r = 0; r < 8; ++r) acc[r] += embs[r][d] * w;
    }
    float* dst = sel ? P2 : P1;
#pragma unroll
    for (int r = 0; r < 8; ++r) {
        int row = row0 + r;
        if (row < nrows) dst[row * 128 + e] = acc[r];
    }
}

// K2: attention + visit embedding x[bv,128]
__global__ __launch_bounds__(256) void k_attention(
    const int* __restrict__ seqs, const int* __restrict__ ancestors,
    const float* __restrict__ amask, const float* __restrict__ emb,
    const float* __restrict__ P1, const float* __restrict__ P2,
    const float* __restrict__ u_w, const float* __restrict__ u_b,
    float* __restrict__ x_out)
{
    __shared__ float u_s[128];
    __shared__ float sc_s[144];
    __shared__ float m_s[144];
    __shared__ int   anc_s[144];
    __shared__ float attn_s[144];
    __shared__ float sum_s[24];
    __shared__ float xred[256];
    int bv = blockIdx.x;
    int t = threadIdx.x;
    if (t < 128) u_s[t] = u_w[t];
    __syncthreads();
    float ub = u_b[0];
    int g = t >> 2, l = t & 3;
    for (int p = g; p < CC * AA; p += 64) {
        int c = p / AA, a = p - c * AA;
        int sidx = bv * CC + c;
        int s_code = seqs[sidx];
        int aidx = sidx * AA + a;
        int anc = ancestors[aidx];
        float m = amask[aidx];
        const float* p1 = P1 + s_code * 128;
        const float* p2 = P2 + anc * 128;
        float partial = 0.0f;
        int e0 = l * 32;
#pragma unroll 8
        for (int j = 0; j < 32; ++j) {
            int e = e0 + j;
            float hv = fast_tanh(m * (p1[e] + p2[e]));
            partial += hv * u_s[e];
        }
        partial += __shfl_xor(partial, 1);
        partial += __shfl_xor(partial, 2);
        if (l == 0) {
            sc_s[p] = partial + ub;
            m_s[p] = m;
            anc_s[p] = anc;
        }
    }
    __syncthreads();
    if (t < CC * AA) attn_s[t] = __expf(sc_s[t]) * m_s[t];
    __syncthreads();
    if (t < CC) {
        float s = 0.0f;
#pragma unroll
        for (int a = 0; a < AA; ++a) s += attn_s[t * AA + a];
        sum_s[t] = (s == 0.0f) ? -1.0f : s;
    }
    __syncthreads();
    if (t < CC * AA) attn_s[t] = attn_s[t] / sum_s[t / AA];
    __syncthreads();
    int e = t & 127, hc = t >> 7;
    float acc = 0.0f;
    for (int c = hc * 12; c < hc * 12 + 12; ++c) {
#pragma unroll
        for (int a = 0; a < AA; ++a) {
            int p = c * AA + a;
            acc += attn_s[p] * emb[anc_s[p] * 128 + e];
        }
    }
    xred[t] = acc;
    __syncthreads();
    if (t < 128) {
        x_out[bv * 128 + t] = fast_tanh(xred[t] + xred[t + 128]);
    }
}

// K3: gi[bv,o] = sum_d x[bv,d]*Wih[o,d] + bih[o]
__global__ __launch_bounds__(384) void k_gi(
    const float* __restrict__ x, const float* __restrict__ wih,
    const float* __restrict__ bih, float* __restrict__ gi)
{
    __shared__ float xs[8][128];
    int row0 = blockIdx.x * 8;
    int t = threadIdx.x;
    for (int i = t; i < 8 * 128; i += 384) {
        int r = i >> 7, d = i & 127;
        xs[r][d] = x[(row0 + r) * 128 + d];
    }
    __syncthreads();
    const float* wrow = wih + t * 128;
    float acc[8] = {0, 0, 0, 0, 0, 0, 0, 0};
#pragma unroll 8
    for (int d = 0; d < 128; ++d) {
        float w = wrow[d];
#pragma unroll
        for (int r = 0; r < 8; ++r) acc[r] += xs[r][d] * w;
    }
    float bb = bih[t];
#pragma unroll
    for (int r = 0; r < 8; ++r) gi[(row0 + r) * G3 + t] = acc[r] + bb;
}

// K4: sequential GRU over V steps + masked context sum + output layer
__global__ __launch_bounds__(768) void k_gru(
    const float* __restrict__ gi, const float* __restrict__ whh,
    const float* __restrict__ bhh, const int* __restrict__ length,
    const float* __restrict__ out_w, const float* __restrict__ out_b,
    float* __restrict__ out)
{
    __shared__ float hs[128];
    __shared__ float part[768];
    __shared__ float bhh_s[384];
    __shared__ float ctxs[128];
    int b = blockIdx.x;
    int t = threadIdx.x;
    int o = t >> 1, half = t & 1;
    // Whh slice resident in registers: thread (o,half) owns Whh[o, half*64 .. +64)
    float rw[64];
    const float* wsrc = whh + o * 128 + half * 64;
#pragma unroll
    for (int j = 0; j < 64; ++j) rw[j] = wsrc[j];
    if (t < 128) hs[t] = 0.0f;
    if (t < 384) bhh_s[t] = bhh[t];
    int len = length[b];
    float ctx = 0.0f;
    __syncthreads();
    const float* gib = gi + b * VV * G3;
    for (int v = 0; v < VV; ++v) {
        // prefetch gi for gate phase (hidden under the partial-dot compute)
        float gir = 0.0f, giz = 0.0f, gin = 0.0f;
        if (t < 128) {
            const float* g = gib + v * G3;
            gir = g[t]; giz = g[128 + t]; gin = g[256 + t];
        }
        float partial = 0.0f;
        const float* hp = hs + half * 64;
#pragma unroll
        for (int j = 0; j < 64; ++j) partial += hp[j] * rw[j];
        part[t] = partial;
        __syncthreads();
        if (t < 128) {
            float gh_r = part[2 * t] + part[2 * t + 1] + bhh_s[t];
            float gh_z = part[2 * (128 + t)] + part[2 * (128 + t) + 1] + bhh_s[128 + t];
            float gh_n = part[2 * (256 + t)] + part[2 * (256 + t) + 1] + bhh_s[256 + t];
            float r = fast_sigmoid(gir + gh_r);
            float z = fast_sigmoid(giz + gh_z);
            float n = fast_tanh(gin + r * gh_n);
            float hnew = (1.0f - z) * n + z * hs[t];
            if (v < len) ctx += hnew;
            hs[t] = hnew;
        }
        __syncthreads();
    }
    if (t < 128) ctxs[t] = ctx;
    __syncthreads();
    if (t < OUTN) {
        const float* wrow = out_w + t * 128;
        float acc = 0.0f;
#pragma unroll 8
        for (int d = 0; d < 128; ++d) acc += ctxs[d] * wrow[d];
        out[b * OUTN + t] = fast_sigmoid(acc + out_b[t]);
    }
}

extern "C" void kernel_launch(void* const* d_in, const int* in_sizes, int n_in,
                              void* d_out, int out_size, void* d_ws, size_t ws_size,
                              hipStream_t stream) {
    const int*   seqs      = (const int*)d_in[0];
    const int*   ancestors = (const int*)d_in[1];
    const int*   length    = (const int*)d_in[2];
    const float* amask     = (const float*)d_in[3];
    const float* emb       = (const float*)d_in[4];
    const float* w_basic   = (const float*)d_in[5];
    const float* u_w       = (const float*)d_in[6];
    const float* u_b       = (const float*)d_in[7];
    const float* wih       = (const float*)d_in[8];
    const float* whh       = (const float*)d_in[9];
    const float* bih       = (const float*)d_in[10];
    const float* bhh       = (const float*)d_in[11];
    const float* out_w     = (const float*)d_in[12];
    const float* out_b     = (const float*)d_in[13];
    float* out = (float*)d_out;

    float* ws = (float*)d_ws;
    float* P1 = ws;                       // [10001,128]
    float* P2 = P1 + NCODES * 128;        // [10001,128]
    float* x  = P2 + NCODES * 128;        // [1536,128]
    float* gi = x + BB * VV * 128;        // [1536,384]

    k_precompute<<<(NCODES + 7) / 8, 256, 0, stream>>>(emb, w_basic, P1, P2, NCODES);
    k_attention<<<BB * VV, 256, 0, stream>>>(seqs, ancestors, amask, emb, P1, P2, u_w, u_b, x);
    k_gi<<<(BB * VV) / 8, 384, 0, stream>>>(x, wih, bih, gi);
    k_gru<<<BB, 768, 0, stream>>>(gi, whh, bhh, length, out_w, out_b, out);
}